// Round 2
// baseline (711.834 us; speedup 1.0000x reference)
//
#include <hip/hip_runtime.h>

#define BB 16
#define NT 2048
#define NC 2048
#define DIM 256
#define INDIM 128

typedef unsigned short u16;
typedef __bf16 bfx8 __attribute__((ext_vector_type(8)));
typedef float f32x4 __attribute__((ext_vector_type(4)));

__device__ __forceinline__ u16 f2bf(float f) {
    union { float f; unsigned u; } v; v.f = f;
    return (u16)((v.u + 0x7FFFu + ((v.u >> 16) & 1u)) >> 16);
}

#define MFMA16(a, b, c) __builtin_amdgcn_mfma_f32_16x16x32_bf16((a), (b), (c), 0, 0, 0)

// ---------------- converts ----------------

__global__ void cvt_bf16_kernel(const float* __restrict__ in, u16* __restrict__ out, int n4) {
    int i = blockIdx.x * blockDim.x + threadIdx.x;
    if (i >= n4) return;
    float4 v = reinterpret_cast<const float4*>(in)[i];
    ushort4 o;
    o.x = f2bf(v.x); o.y = f2bf(v.y); o.z = f2bf(v.z); o.w = f2bf(v.w);
    reinterpret_cast<ushort4*>(out)[i] = o;
}

// w [K][256] fp32 -> wt [256][K] bf16
__global__ void cvt_w_kernel(const float* __restrict__ w, u16* __restrict__ wt, int K) {
    int idx = blockIdx.x * 256 + threadIdx.x;
    if (idx >= K * 256) return;
    int n = idx / K, k = idx - n * K;
    wt[idx] = f2bf(w[k * 256 + n]);
}

// r [B][NC][DIM] fp32 -> rt [B][DIM][NC] bf16
__global__ void cvt_rt_kernel(const float* __restrict__ r, u16* __restrict__ rt) {
    __shared__ u16 tile[32][33];
    int b = blockIdx.z;
    int c0 = blockIdx.x * 32, d0 = blockIdx.y * 32;
    int tx = threadIdx.x, ty = threadIdx.y; // (32, 8)
    const float* rb = r + (size_t)b * NC * DIM;
#pragma unroll
    for (int i = 0; i < 4; i++) {
        int c = c0 + ty + i * 8;
        tile[ty + i * 8][tx] = f2bf(rb[(size_t)c * DIM + d0 + tx]);
    }
    __syncthreads();
    u16* rtb = rt + (size_t)b * DIM * NC;
#pragma unroll
    for (int i = 0; i < 4; i++) {
        int d = d0 + ty + i * 8;
        rtb[(size_t)d * NC + c0 + tx] = tile[tx][ty + i * 8];
    }
}

// ---------------- MLP GEMM: C[M,256] = act(A[M,K] @ Wt[256,K]^T + bias) ----------------

template <int K, bool RELU>
__global__ __launch_bounds__(256) void gemm_mlp(const u16* __restrict__ A,
                                                const u16* __restrict__ Wt,
                                                const float* __restrict__ bias,
                                                u16* __restrict__ C) {
    int tid = threadIdx.x;
    int lane = tid & 63, wid = tid >> 6;
    int wr = wid >> 1, wc = wid & 1;
    int m0 = blockIdx.x * 128 + wr * 64;
    int n0 = blockIdx.y * 128 + wc * 64;
    int lr = lane & 15, lg = lane >> 4;

    f32x4 acc[4][4] = {};
#pragma unroll
    for (int ks = 0; ks < K / 32; ks++) {
        bfx8 a[4], b[4];
#pragma unroll
        for (int mt = 0; mt < 4; mt++)
            a[mt] = *reinterpret_cast<const bfx8*>(A + (size_t)(m0 + mt * 16 + lr) * K + ks * 32 + lg * 8);
#pragma unroll
        for (int nt = 0; nt < 4; nt++)
            b[nt] = *reinterpret_cast<const bfx8*>(Wt + (size_t)(n0 + nt * 16 + lr) * K + ks * 32 + lg * 8);
#pragma unroll
        for (int mt = 0; mt < 4; mt++)
#pragma unroll
            for (int nt = 0; nt < 4; nt++)
                acc[mt][nt] = MFMA16(a[mt], b[nt], acc[mt][nt]);
    }
#pragma unroll
    for (int nt = 0; nt < 4; nt++) {
        int col = n0 + nt * 16 + lr;
        float bv = bias[col];
#pragma unroll
        for (int mt = 0; mt < 4; mt++) {
            int rowb = m0 + mt * 16 + lg * 4;
#pragma unroll
            for (int r = 0; r < 4; r++) {
                float v = acc[mt][nt][r] + bv;
                if (RELU) v = fmaxf(v, 0.0f);
                C[(size_t)(rowb + r) * 256 + col] = f2bf(v);
            }
        }
    }
}

// ---------------- pass 1: column stats m_c, 1/l_c ----------------

__global__ __launch_bounds__(256) void stats_kernel(const u16* __restrict__ q,
                                                    const u16* __restrict__ k,
                                                    float* __restrict__ gm,
                                                    float* __restrict__ gl) {
    int b = blockIdx.y;
    int c0 = blockIdx.x * 64;
    int tid = threadIdx.x, lane = tid & 63, w = tid >> 6;
    int lr = lane & 15, lg = lane >> 4;
    const u16* qb = q + (size_t)b * NT * DIM;
    const u16* kb = k + (size_t)b * NC * DIM;
    const float scale = 1.0f / 16.0f;

    bfx8 kf[4][8];
#pragma unroll
    for (int j = 0; j < 4; j++)
#pragma unroll
        for (int ks = 0; ks < 8; ks++)
            kf[j][ks] = *reinterpret_cast<const bfx8*>(kb + (size_t)(c0 + j * 16 + lr) * DIM + ks * 32 + lg * 8);

    float m_run[4], l_run[4];
#pragma unroll
    for (int j = 0; j < 4; j++) { m_run[j] = -1e30f; l_run[j] = 0.0f; }

    for (int ts = 0; ts < NT / 64; ts++) {
        int t0 = ts * 64 + w * 16;
        f32x4 acc[4] = {};
#pragma unroll
        for (int ks = 0; ks < 8; ks++) {
            bfx8 a = *reinterpret_cast<const bfx8*>(qb + (size_t)(t0 + lr) * DIM + ks * 32 + lg * 8);
#pragma unroll
            for (int j = 0; j < 4; j++)
                acc[j] = MFMA16(a, kf[j][ks], acc[j]);
        }
#pragma unroll
        for (int j = 0; j < 4; j++) {
            float s0 = acc[j][0] * scale, s1 = acc[j][1] * scale;
            float s2 = acc[j][2] * scale, s3 = acc[j][3] * scale;
            float mx = fmaxf(fmaxf(s0, s1), fmaxf(s2, s3));
            mx = fmaxf(mx, __shfl_xor(mx, 16));
            mx = fmaxf(mx, __shfl_xor(mx, 32));
            float m_new = fmaxf(m_run[j], mx);
            float p = __expf(s0 - m_new) + __expf(s1 - m_new) + __expf(s2 - m_new) + __expf(s3 - m_new);
            p += __shfl_xor(p, 16);
            p += __shfl_xor(p, 32);
            l_run[j] = l_run[j] * __expf(m_run[j] - m_new) + p;
            m_run[j] = m_new;
        }
    }

    __shared__ float sm[4][64], sl[4][64];
    if (lg == 0) {
#pragma unroll
        for (int j = 0; j < 4; j++) {
            sm[w][j * 16 + lr] = m_run[j];
            sl[w][j * 16 + lr] = l_run[j];
        }
    }
    __syncthreads();
    if (tid < 64) {
        float mf = sm[0][tid];
#pragma unroll
        for (int ww = 1; ww < 4; ww++) mf = fmaxf(mf, sm[ww][tid]);
        float lf = 0.0f;
#pragma unroll
        for (int ww = 0; ww < 4; ww++) lf += sl[ww][tid] * __expf(sm[ww][tid] - mf);
        gm[(size_t)b * NC + c0 + tid] = mf;
        gl[(size_t)b * NC + c0 + tid] = 1.0f / lf;
    }
}

// ---------------- pass 2: out[t,d] = sum_c exp(S-m_c)/l_c * r[c,d] ----------------
// grid (NT/64, B), 256 threads = 4 INDEPENDENT waves. Wave w owns 16 t-rows
// (t0 = blk*64 + w*16) and computes ALL 256 output dims for them. P tile is
// wave-private LDS -> NO __syncthreads in the main loop (wave-lockstep + DS
// in-order; explicit lgkmcnt(0)+sched_barrier orders write->read, rule #18).

__global__ __launch_bounds__(256, 2) void attn_kernel(const u16* __restrict__ q,
                                                      const u16* __restrict__ k,
                                                      const u16* __restrict__ rt,
                                                      const float* __restrict__ gm,
                                                      const float* __restrict__ gl,
                                                      float* __restrict__ out) {
    int b = blockIdx.y;
    int tid = threadIdx.x, lane = tid & 63, w = tid >> 6;
    int t0 = blockIdx.x * 64 + w * 16;
    int lr = lane & 15, lg = lane >> 4;
    const u16* qb = q + (size_t)b * NT * DIM;
    const u16* kb = k + (size_t)b * NC * DIM;
    const u16* rtb = rt + (size_t)b * DIM * NC;

    __shared__ float sm[NC], sl[NC];           // m_c * log2e, 1/l_c
    __shared__ __bf16 pl[4][16][40];           // per-wave P tile, padded (80B row)

    for (int i = tid; i < NC; i += 256) {
        sm[i] = gm[(size_t)b * NC + i] * 1.44269504f;
        sl[i] = gl[(size_t)b * NC + i];
    }
    __syncthreads();  // only barrier in the kernel

    // hoist q fragments (wave's 16 rows, full K=256)
    bfx8 aq[8];
#pragma unroll
    for (int ks = 0; ks < 8; ks++)
        aq[ks] = *reinterpret_cast<const bfx8*>(qb + (size_t)(t0 + lr) * DIM + ks * 32 + lg * 8);

    const float A = 1.44269504f / 16.0f;  // log2e * scale
    f32x4 acc[16] = {};

    for (int c0 = 0; c0 < NC; c0 += 32) {
        // S phase: S[16t x 32c] = Q @ K^T  (K direct from global; L1/L2-hit)
        f32x4 s[2] = {};
#pragma unroll
        for (int ks = 0; ks < 8; ks++) {
#pragma unroll
            for (int j = 0; j < 2; j++) {
                bfx8 bb = *reinterpret_cast<const bfx8*>(kb + (size_t)(c0 + j * 16 + lr) * DIM + ks * 32 + lg * 8);
                s[j] = MFMA16(aq[ks], bb, s[j]);
            }
        }
        // P = exp2(S*A - m*log2e) * invl, write to wave-private LDS
#pragma unroll
        for (int j = 0; j < 2; j++) {
            int c = c0 + j * 16 + lr;
            float bc = sm[c], lv = sl[c];
#pragma unroll
            for (int r = 0; r < 4; r++) {
                float p = exp2f(fmaf(s[j][r], A, -bc)) * lv;
                pl[w][lg * 4 + r][j * 16 + lr] = (__bf16)p;
            }
        }
        __builtin_amdgcn_sched_barrier(0);
        asm volatile("s_waitcnt lgkmcnt(0)" ::: "memory");
        __builtin_amdgcn_sched_barrier(0);
        // PV phase: acc[16t x 256d] += P @ rt^T (rt direct from global)
        bfx8 pa = *reinterpret_cast<const bfx8*>(&pl[w][lr][lg * 8]);
#pragma unroll
        for (int nt = 0; nt < 16; nt++) {
            bfx8 rb = *reinterpret_cast<const bfx8*>(rtb + (size_t)(nt * 16 + lr) * NC + c0 + lg * 8);
            acc[nt] = MFMA16(pa, rb, acc[nt]);
        }
    }

    float* ob = out + (size_t)b * NT * DIM;
#pragma unroll
    for (int nt = 0; nt < 16; nt++) {
#pragma unroll
        for (int r = 0; r < 4; r++)
            ob[(size_t)(t0 + lg * 4 + r) * DIM + nt * 16 + lr] = acc[nt][r];
    }
}

// ---------------- launch ----------------

extern "C" void kernel_launch(void* const* d_in, const int* in_sizes, int n_in,
                              void* d_out, int out_size, void* d_ws, size_t ws_size,
                              hipStream_t stream) {
    const float* xc  = (const float*)d_in[0];
    const float* xt  = (const float*)d_in[1];
    const float* ri  = (const float*)d_in[2];
    const float* qw1 = (const float*)d_in[3];  const float* qb1 = (const float*)d_in[4];
    const float* qw2 = (const float*)d_in[5];  const float* qb2 = (const float*)d_in[6];
    const float* qw3 = (const float*)d_in[7];  const float* qb3 = (const float*)d_in[8];
    const float* kw1 = (const float*)d_in[9];  const float* kb1 = (const float*)d_in[10];
    const float* kw2 = (const float*)d_in[11]; const float* kb2 = (const float*)d_in[12];
    const float* kw3 = (const float*)d_in[13]; const float* kb3 = (const float*)d_in[14];

    if (ws_size < ((size_t)67 << 20)) return;  // need ~65.3 MB

    char* ws = (char*)d_ws;
    u16* q    = (u16*)(ws);                         // 16 MB: q bf16 [B][NT][DIM]
    u16* kk   = (u16*)(ws + ((size_t)16 << 20));    // 16 MB: k bf16 [B][NC][DIM]
    u16* tmp1 = (u16*)(ws + ((size_t)32 << 20));    // 16 MB: x / h2 / rt
    u16* tmp2 = (u16*)(ws + ((size_t)48 << 20));    // 16 MB: h1
    u16* wbuf = (u16*)(ws + ((size_t)64 << 20));    // 640 KB weights
    u16* qw1t = wbuf;
    u16* qw2t = qw1t + 32768;
    u16* qw3t = qw2t + 65536;
    u16* kw1t = qw3t + 65536;
    u16* kw2t = kw1t + 32768;
    u16* kw3t = kw2t + 65536;
    float* gm = (float*)(ws + ((size_t)65 << 20));
    float* gl = gm + BB * NC;

    // weights -> transposed bf16
    cvt_w_kernel<<<dim3(128), 256, 0, stream>>>(qw1, qw1t, 128);
    cvt_w_kernel<<<dim3(256), 256, 0, stream>>>(qw2, qw2t, 256);
    cvt_w_kernel<<<dim3(256), 256, 0, stream>>>(qw3, qw3t, 256);
    cvt_w_kernel<<<dim3(128), 256, 0, stream>>>(kw1, kw1t, 128);
    cvt_w_kernel<<<dim3(256), 256, 0, stream>>>(kw2, kw2t, 256);
    cvt_w_kernel<<<dim3(256), 256, 0, stream>>>(kw3, kw3t, 256);

    // q-MLP
    cvt_bf16_kernel<<<4096, 256, 0, stream>>>(xt, tmp1, (BB * NT * INDIM) / 4);
    gemm_mlp<128, true ><<<dim3(256, 2), 256, 0, stream>>>(tmp1, qw1t, qb1, tmp2);
    gemm_mlp<256, true ><<<dim3(256, 2), 256, 0, stream>>>(tmp2, qw2t, qb2, tmp1);
    gemm_mlp<256, false><<<dim3(256, 2), 256, 0, stream>>>(tmp1, qw3t, qb3, q);

    // k-MLP
    cvt_bf16_kernel<<<4096, 256, 0, stream>>>(xc, tmp1, (BB * NC * INDIM) / 4);
    gemm_mlp<128, true ><<<dim3(256, 2), 256, 0, stream>>>(tmp1, kw1t, kb1, tmp2);
    gemm_mlp<256, true ><<<dim3(256, 2), 256, 0, stream>>>(tmp2, kw2t, kb2, tmp1);
    gemm_mlp<256, false><<<dim3(256, 2), 256, 0, stream>>>(tmp1, kw3t, kb3, kk);

    // r_i -> rt (transposed bf16)
    cvt_rt_kernel<<<dim3(64, 8, BB), dim3(32, 8), 0, stream>>>(ri, tmp1);

    // pass 1: column stats
    stats_kernel<<<dim3(NC / 64, BB), 256, 0, stream>>>(q, kk, gm, gl);

    // pass 2: attention output
    attn_kernel<<<dim3(NT / 64, BB), 256, 0, stream>>>(q, kk, tmp1, gm, gl, (float*)d_out);
}

// Round 3
// 340.023 us; speedup vs baseline: 2.0935x; 2.0935x over previous
//
#include <hip/hip_runtime.h>

#define BB 16
#define NT 2048
#define NC 2048
#define DIM 256
#define INDIM 128

typedef unsigned short u16;
typedef __bf16 bfx8 __attribute__((ext_vector_type(8)));
typedef __bf16 bfx8a __attribute__((ext_vector_type(8), aligned(8)));
typedef float f32x4 __attribute__((ext_vector_type(4)));

__device__ __forceinline__ u16 f2bf(float f) {
    union { float f; unsigned u; } v; v.f = f;
    return (u16)((v.u + 0x7FFFu + ((v.u >> 16) & 1u)) >> 16);
}

#define MFMA16(a, b, c) __builtin_amdgcn_mfma_f32_16x16x32_bf16((a), (b), (c), 0, 0, 0)

// ---------------- converts ----------------

__global__ void cvt_bf16_kernel(const float* __restrict__ in, u16* __restrict__ out, int n4) {
    int i = blockIdx.x * blockDim.x + threadIdx.x;
    if (i >= n4) return;
    float4 v = reinterpret_cast<const float4*>(in)[i];
    ushort4 o;
    o.x = f2bf(v.x); o.y = f2bf(v.y); o.z = f2bf(v.z); o.w = f2bf(v.w);
    reinterpret_cast<ushort4*>(out)[i] = o;
}

// w [K][256] fp32 -> wt [256][K] bf16
__global__ void cvt_w_kernel(const float* __restrict__ w, u16* __restrict__ wt, int K) {
    int idx = blockIdx.x * 256 + threadIdx.x;
    if (idx >= K * 256) return;
    int n = idx / K, k = idx - n * K;
    wt[idx] = f2bf(w[k * 256 + n]);
}

// r [B][NC][DIM] fp32 -> rt [B][DIM][NC] bf16
__global__ void cvt_rt_kernel(const float* __restrict__ r, u16* __restrict__ rt) {
    __shared__ u16 tile[32][33];
    int b = blockIdx.z;
    int c0 = blockIdx.x * 32, d0 = blockIdx.y * 32;
    int tx = threadIdx.x, ty = threadIdx.y; // (32, 8)
    const float* rb = r + (size_t)b * NC * DIM;
#pragma unroll
    for (int i = 0; i < 4; i++) {
        int c = c0 + ty + i * 8;
        tile[ty + i * 8][tx] = f2bf(rb[(size_t)c * DIM + d0 + tx]);
    }
    __syncthreads();
    u16* rtb = rt + (size_t)b * DIM * NC;
#pragma unroll
    for (int i = 0; i < 4; i++) {
        int d = d0 + ty + i * 8;
        rtb[(size_t)d * NC + c0 + tx] = tile[tx][ty + i * 8];
    }
}

// ---------------- MLP GEMM: C[M,256] = act(A[M,K] @ Wt[256,K]^T + bias) ----------------

template <int K, bool RELU>
__global__ __launch_bounds__(256) void gemm_mlp(const u16* __restrict__ A,
                                                const u16* __restrict__ Wt,
                                                const float* __restrict__ bias,
                                                u16* __restrict__ C) {
    int tid = threadIdx.x;
    int lane = tid & 63, wid = tid >> 6;
    int wr = wid >> 1, wc = wid & 1;
    int m0 = blockIdx.x * 128 + wr * 64;
    int n0 = blockIdx.y * 128 + wc * 64;
    int lr = lane & 15, lg = lane >> 4;

    f32x4 acc[4][4] = {};
#pragma unroll
    for (int ks = 0; ks < K / 32; ks++) {
        bfx8 a[4], b[4];
#pragma unroll
        for (int mt = 0; mt < 4; mt++)
            a[mt] = *reinterpret_cast<const bfx8*>(A + (size_t)(m0 + mt * 16 + lr) * K + ks * 32 + lg * 8);
#pragma unroll
        for (int nt = 0; nt < 4; nt++)
            b[nt] = *reinterpret_cast<const bfx8*>(Wt + (size_t)(n0 + nt * 16 + lr) * K + ks * 32 + lg * 8);
#pragma unroll
        for (int mt = 0; mt < 4; mt++)
#pragma unroll
            for (int nt = 0; nt < 4; nt++)
                acc[mt][nt] = MFMA16(a[mt], b[nt], acc[mt][nt]);
    }
#pragma unroll
    for (int nt = 0; nt < 4; nt++) {
        int col = n0 + nt * 16 + lr;
        float bv = bias[col];
#pragma unroll
        for (int mt = 0; mt < 4; mt++) {
            int rowb = m0 + mt * 16 + lg * 4;
#pragma unroll
            for (int r = 0; r < 4; r++) {
                float v = acc[mt][nt][r] + bv;
                if (RELU) v = fmaxf(v, 0.0f);
                C[(size_t)(rowb + r) * 256 + col] = f2bf(v);
            }
        }
    }
}

// ---------------- pass 1: column stats -> gs[c] = (m_c * log2e, 1/l_c) ----------------

__global__ __launch_bounds__(256) void stats_kernel(const u16* __restrict__ q,
                                                    const u16* __restrict__ k,
                                                    float2* __restrict__ gso) {
    int b = blockIdx.y;
    int c0 = blockIdx.x * 64;
    int tid = threadIdx.x, lane = tid & 63, w = tid >> 6;
    int lr = lane & 15, lg = lane >> 4;
    const u16* qb = q + (size_t)b * NT * DIM;
    const u16* kb = k + (size_t)b * NC * DIM;
    const float scale = 1.0f / 16.0f;

    bfx8 kf[4][8];
#pragma unroll
    for (int j = 0; j < 4; j++)
#pragma unroll
        for (int ks = 0; ks < 8; ks++)
            kf[j][ks] = *reinterpret_cast<const bfx8*>(kb + (size_t)(c0 + j * 16 + lr) * DIM + ks * 32 + lg * 8);

    float m_run[4], l_run[4];
#pragma unroll
    for (int j = 0; j < 4; j++) { m_run[j] = -1e30f; l_run[j] = 0.0f; }

    for (int ts = 0; ts < NT / 64; ts++) {
        int t0 = ts * 64 + w * 16;
        f32x4 acc[4] = {};
#pragma unroll
        for (int ks = 0; ks < 8; ks++) {
            bfx8 a = *reinterpret_cast<const bfx8*>(qb + (size_t)(t0 + lr) * DIM + ks * 32 + lg * 8);
#pragma unroll
            for (int j = 0; j < 4; j++)
                acc[j] = MFMA16(a, kf[j][ks], acc[j]);
        }
#pragma unroll
        for (int j = 0; j < 4; j++) {
            float s0 = acc[j][0] * scale, s1 = acc[j][1] * scale;
            float s2 = acc[j][2] * scale, s3 = acc[j][3] * scale;
            float mx = fmaxf(fmaxf(s0, s1), fmaxf(s2, s3));
            mx = fmaxf(mx, __shfl_xor(mx, 16));
            mx = fmaxf(mx, __shfl_xor(mx, 32));
            float m_new = fmaxf(m_run[j], mx);
            float p = __expf(s0 - m_new) + __expf(s1 - m_new) + __expf(s2 - m_new) + __expf(s3 - m_new);
            p += __shfl_xor(p, 16);
            p += __shfl_xor(p, 32);
            l_run[j] = l_run[j] * __expf(m_run[j] - m_new) + p;
            m_run[j] = m_new;
        }
    }

    __shared__ float sm[4][64], sl[4][64];
    if (lg == 0) {
#pragma unroll
        for (int j = 0; j < 4; j++) {
            sm[w][j * 16 + lr] = m_run[j];
            sl[w][j * 16 + lr] = l_run[j];
        }
    }
    __syncthreads();
    if (tid < 64) {
        float mf = sm[0][tid];
#pragma unroll
        for (int ww = 1; ww < 4; ww++) mf = fmaxf(mf, sm[ww][tid]);
        float lf = 0.0f;
#pragma unroll
        for (int ww = 0; ww < 4; ww++) lf += sl[ww][tid] * __expf(sm[ww][tid] - mf);
        gso[(size_t)b * NC + c0 + tid] = make_float2(mf * 1.44269504f, 1.0f / lf);
    }
}

// ---------------- pass 2: pipelined (T3/T4: counted vmcnt, no drain-0 in loop) ----------
// grid (NT/64, B), 256 threads, 4 waves. Wave w: S rows [16w,16w+16), out cols [64w,64w+64).
// K tiles: global_load_lds dbuf, XOR-swizzled via pre-swizzled global src (rule #21).
// rt frags: register prefetch one iter ahead. Barriers: raw s_barrier, lgkm-only at P
// hand-off, vmcnt(4) stage-drain at iter end. sched_barrier(0) pins issue order.

__global__ __launch_bounds__(256, 2) void attn_kernel(const u16* __restrict__ q,
                                                      const u16* __restrict__ k,
                                                      const u16* __restrict__ rt,
                                                      const float2* __restrict__ gsg_,
                                                      float* __restrict__ out) {
    int b = blockIdx.y;
    int tid = threadIdx.x, lane = tid & 63, w = tid >> 6;
    int t0 = blockIdx.x * 64;
    int lr = lane & 15, lg = lane >> 4;
    const u16* qb = q + (size_t)b * NT * DIM;
    const u16* kb = k + (size_t)b * NC * DIM;
    const u16* rtb = rt + (size_t)b * DIM * NC;

    __shared__ float2 gs[NC];                       // 16 KB
    __shared__ __align__(16) u16 kt[2][32 * 256];   // 2 x 16 KB, swizzled K tiles
    __shared__ u16 pl[64][36];                      // P tile, 72B rows (write conflict-free)

    {
        const float2* gsg = gsg_ + (size_t)b * NC;
        for (int i = tid; i < NC; i += 256) gs[i] = gsg[i];
    }
    __syncthreads();

#define STAGE(nb, cc) do {                                                          \
    const u16* ksrc_ = kb + (size_t)(cc) * DIM;                                     \
    _Pragma("unroll")                                                               \
    for (int i_ = 0; i_ < 4; i_++) {                                                \
        int off_ = ((w * 4 + i_) << 10) + (lane << 4);                              \
        int row_ = off_ >> 9;                                                       \
        int ss_  = ((off_ >> 4) & 31) ^ (row_ & 7);                                 \
        const u16* g_ = ksrc_ + row_ * DIM + ss_ * 8;                               \
        __builtin_amdgcn_global_load_lds(                                           \
            (const __attribute__((address_space(1))) void*)g_,                      \
            (__attribute__((address_space(3))) void*)(&kt[nb][(w * 4 + i_) << 9]),  \
            16, 0, 0);                                                              \
    }                                                                               \
} while (0)

    // prologue: stage tile 0, prefetch rb for tile 0, hoist q
    STAGE(0, 0);
    __builtin_amdgcn_sched_barrier(0);
    bfx8 rb_c[4], rb_n[4];
#pragma unroll
    for (int nt = 0; nt < 4; nt++)
        rb_c[nt] = *reinterpret_cast<const bfx8*>(rtb + (size_t)(w * 64 + nt * 16 + lr) * NC + lg * 8);
    bfx8 aq[8];
#pragma unroll
    for (int ks = 0; ks < 8; ks++)
        aq[ks] = *reinterpret_cast<const bfx8*>(qb + (size_t)(t0 + w * 16 + lr) * DIM + ks * 32 + lg * 8);
    __builtin_amdgcn_sched_barrier(0);
    asm volatile("s_waitcnt vmcnt(12)");   // drain 4 stage issues (12 newer: 4 rb + 8 aq)
    __builtin_amdgcn_s_barrier();
    __builtin_amdgcn_sched_barrier(0);

    const float A = 1.44269504f / 16.0f;   // log2e * (1/sqrt(256))
    const int key = lr & 7;
    f32x4 acc[4][4] = {};
    int cur = 0;

    for (int c0 = 0; c0 < NC; c0 += 32) {
        const bool last = (c0 + 32 >= NC);
        // issue next tile's loads first (stage oldest in vmcnt FIFO)
        if (!last) STAGE(cur ^ 1, c0 + 32);
        __builtin_amdgcn_sched_barrier(0);
        if (!last) {
#pragma unroll
            for (int nt = 0; nt < 4; nt++)
                rb_n[nt] = *reinterpret_cast<const bfx8*>(rtb + (size_t)(w * 64 + nt * 16 + lr) * NC + (c0 + 32) + lg * 8);
        }

        // S phase: read swizzled kt[cur], 16 MFMAs
        f32x4 s[2] = {};
        {
            const char* kc = (const char*)&kt[cur][0];
#pragma unroll
            for (int ks = 0; ks < 8; ks++) {
                int slot = (ks << 2) | lg;
                bfx8 k0 = *reinterpret_cast<const bfx8*>(kc + (lr << 9) + (((slot ^ key)) << 4));
                bfx8 k1 = *reinterpret_cast<const bfx8*>(kc + ((16 + lr) << 9) + (((slot ^ key)) << 4));
                s[0] = MFMA16(aq[ks], k0, s[0]);
                s[1] = MFMA16(aq[ks], k1, s[1]);
            }
        }
        // P = exp2(S*A - m') * invl -> LDS
#pragma unroll
        for (int j = 0; j < 2; j++) {
            float2 g = gs[c0 + j * 16 + lr];
#pragma unroll
            for (int r = 0; r < 4; r++) {
                float p = exp2f(fmaf(s[j][r], A, -g.x)) * g.y;
                __bf16 h = (__bf16)p;
                pl[w * 16 + lg * 4 + r][j * 16 + lr] = *(u16*)&h;
            }
        }
        // cluster 1: P hand-off (lgkm only; stages/rb stay in flight)
        __builtin_amdgcn_sched_barrier(0);
        asm volatile("s_waitcnt lgkmcnt(0)");
        __builtin_amdgcn_s_barrier();
        __builtin_amdgcn_sched_barrier(0);

        // PV phase: acc += P @ rt  (rb_c prefetched last iter)
#pragma unroll
        for (int mt = 0; mt < 4; mt++) {
            bfx8a pa = *reinterpret_cast<const bfx8a*>((const char*)pl + (mt * 16 + lr) * 72 + lg * 16);
#pragma unroll
            for (int nt = 0; nt < 4; nt++)
                acc[mt][nt] = MFMA16((bfx8)pa, rb_c[nt], acc[mt][nt]);
        }

        // cluster 2: stage drain (vmcnt(4) leaves rb_n in flight) + P-recycle barrier
        __builtin_amdgcn_sched_barrier(0);
        asm volatile("s_waitcnt vmcnt(4) lgkmcnt(0)");
        __builtin_amdgcn_s_barrier();
        __builtin_amdgcn_sched_barrier(0);

#pragma unroll
        for (int nt = 0; nt < 4; nt++) rb_c[nt] = rb_n[nt];
        cur ^= 1;
    }
#undef STAGE

    float* ob = out + (size_t)b * NT * DIM;
#pragma unroll
    for (int nt = 0; nt < 4; nt++) {
        int col = w * 64 + nt * 16 + lr;
#pragma unroll
        for (int mt = 0; mt < 4; mt++) {
            int rowb = t0 + mt * 16 + lg * 4;
#pragma unroll
            for (int r = 0; r < 4; r++)
                ob[(size_t)(rowb + r) * DIM + col] = acc[mt][nt][r];
        }
    }
}

// ---------------- launch ----------------

extern "C" void kernel_launch(void* const* d_in, const int* in_sizes, int n_in,
                              void* d_out, int out_size, void* d_ws, size_t ws_size,
                              hipStream_t stream) {
    const float* xc  = (const float*)d_in[0];
    const float* xt  = (const float*)d_in[1];
    const float* ri  = (const float*)d_in[2];
    const float* qw1 = (const float*)d_in[3];  const float* qb1 = (const float*)d_in[4];
    const float* qw2 = (const float*)d_in[5];  const float* qb2 = (const float*)d_in[6];
    const float* qw3 = (const float*)d_in[7];  const float* qb3 = (const float*)d_in[8];
    const float* kw1 = (const float*)d_in[9];  const float* kb1 = (const float*)d_in[10];
    const float* kw2 = (const float*)d_in[11]; const float* kb2 = (const float*)d_in[12];
    const float* kw3 = (const float*)d_in[13]; const float* kb3 = (const float*)d_in[14];

    if (ws_size < ((size_t)67 << 20)) return;  // need ~65.5 MB

    char* ws = (char*)d_ws;
    u16* q    = (u16*)(ws);                         // 16 MB: q bf16 [B][NT][DIM]
    u16* kk   = (u16*)(ws + ((size_t)16 << 20));    // 16 MB: k bf16 [B][NC][DIM]
    u16* tmp1 = (u16*)(ws + ((size_t)32 << 20));    // 16 MB: x / h2 / rt
    u16* tmp2 = (u16*)(ws + ((size_t)48 << 20));    // 16 MB: h1
    u16* wbuf = (u16*)(ws + ((size_t)64 << 20));    // 640 KB weights
    u16* qw1t = wbuf;
    u16* qw2t = qw1t + 32768;
    u16* qw3t = qw2t + 65536;
    u16* kw1t = qw3t + 65536;
    u16* kw2t = kw1t + 32768;
    u16* kw3t = kw2t + 65536;
    float2* gsb = (float2*)(ws + ((size_t)65 << 20));  // 256 KB col stats

    // weights -> transposed bf16
    cvt_w_kernel<<<dim3(128), 256, 0, stream>>>(qw1, qw1t, 128);
    cvt_w_kernel<<<dim3(256), 256, 0, stream>>>(qw2, qw2t, 256);
    cvt_w_kernel<<<dim3(256), 256, 0, stream>>>(qw3, qw3t, 256);
    cvt_w_kernel<<<dim3(128), 256, 0, stream>>>(kw1, kw1t, 128);
    cvt_w_kernel<<<dim3(256), 256, 0, stream>>>(kw2, kw2t, 256);
    cvt_w_kernel<<<dim3(256), 256, 0, stream>>>(kw3, kw3t, 256);

    // q-MLP
    cvt_bf16_kernel<<<4096, 256, 0, stream>>>(xt, tmp1, (BB * NT * INDIM) / 4);
    gemm_mlp<128, true ><<<dim3(256, 2), 256, 0, stream>>>(tmp1, qw1t, qb1, tmp2);
    gemm_mlp<256, true ><<<dim3(256, 2), 256, 0, stream>>>(tmp2, qw2t, qb2, tmp1);
    gemm_mlp<256, false><<<dim3(256, 2), 256, 0, stream>>>(tmp1, qw3t, qb3, q);

    // k-MLP
    cvt_bf16_kernel<<<4096, 256, 0, stream>>>(xc, tmp1, (BB * NC * INDIM) / 4);
    gemm_mlp<128, true ><<<dim3(256, 2), 256, 0, stream>>>(tmp1, kw1t, kb1, tmp2);
    gemm_mlp<256, true ><<<dim3(256, 2), 256, 0, stream>>>(tmp2, kw2t, kb2, tmp1);
    gemm_mlp<256, false><<<dim3(256, 2), 256, 0, stream>>>(tmp1, kw3t, kb3, kk);

    // r_i -> rt (transposed bf16)
    cvt_rt_kernel<<<dim3(64, 8, BB), dim3(32, 8), 0, stream>>>(ri, tmp1);

    // pass 1: column stats
    stats_kernel<<<dim3(NC / 64, BB), 256, 0, stream>>>(q, kk, gsb);

    // pass 2: attention output
    attn_kernel<<<dim3(NT / 64, BB), 256, 0, stream>>>(q, kk, tmp1, gsb, (float*)d_out);
}

// Round 4
// 286.390 us; speedup vs baseline: 2.4855x; 1.1873x over previous
//
#include <hip/hip_runtime.h>

#define BB 16
#define NT 2048
#define NC 2048
#define DIM 256
#define INDIM 128

typedef unsigned short u16;
typedef __bf16 bfx8 __attribute__((ext_vector_type(8)));
typedef __bf16 bfx8a __attribute__((ext_vector_type(8), aligned(8)));
typedef float f32x4 __attribute__((ext_vector_type(4)));

__device__ __forceinline__ u16 f2bf(float f) {
    union { float f; unsigned u; } v; v.f = f;
    return (u16)((v.u + 0x7FFFu + ((v.u >> 16) & 1u)) >> 16);
}

#define MFMA16(a, b, c) __builtin_amdgcn_mfma_f32_16x16x32_bf16((a), (b), (c), 0, 0, 0)

// ---------------- small converts ----------------

// w [K][256] fp32 -> wt [256][K] bf16
__global__ void cvt_w_kernel(const float* __restrict__ w, u16* __restrict__ wt, int K) {
    int idx = blockIdx.x * 256 + threadIdx.x;
    if (idx >= K * 256) return;
    int n = idx / K, k = idx - n * K;
    wt[idx] = f2bf(w[k * 256 + n]);
}

// r [B][NC][DIM] fp32 -> rt [B][DIM][NC] bf16
__global__ void cvt_rt_kernel(const float* __restrict__ r, u16* __restrict__ rt) {
    __shared__ u16 tile[32][33];
    int b = blockIdx.z;
    int c0 = blockIdx.x * 32, d0 = blockIdx.y * 32;
    int tx = threadIdx.x, ty = threadIdx.y; // (32, 8)
    const float* rb = r + (size_t)b * NC * DIM;
#pragma unroll
    for (int i = 0; i < 4; i++) {
        int c = c0 + ty + i * 8;
        tile[ty + i * 8][tx] = f2bf(rb[(size_t)c * DIM + d0 + tx]);
    }
    __syncthreads();
    u16* rtb = rt + (size_t)b * DIM * NC;
#pragma unroll
    for (int i = 0; i < 4; i++) {
        int d = d0 + ty + i * 8;
        rtb[(size_t)d * NC + c0 + tx] = tile[tx][ty + i * 8];
    }
}

// ---------------- fused MLP layer: C[M,256] = act(A[M,K] @ Wt[256,K]^T + b) --------------
// grid (M/128, 2): y=0 -> q path, y=1 -> k path. 4 waves; wave w = 128 rows x cols [64w,64w+64).
// A-tile (128 x K) staged in LDS, XOR-swizzled (^((row&7)<<4)).
// CVTIN: A is fp32 (layer 1) -> reg-stage + convert + swizzled ds_write.
// else:  A is bf16 -> global_load_lds with pre-swizzled source (linear dest, rule #21).

template <int K, bool RELU, bool CVTIN>
__global__ __launch_bounds__(256) void mlp_gemm(const void* __restrict__ Aq, const void* __restrict__ Ak,
                                                const u16* __restrict__ Wq, const u16* __restrict__ Wk,
                                                const float* __restrict__ bq, const float* __restrict__ bk,
                                                u16* __restrict__ Cq, u16* __restrict__ Ck) {
    constexpr int ROWB = K * 2;          // A-tile row bytes (bf16)
    constexpr int NCH = K / 16;          // 16B chunks per thread for 128xK bf16 tile
    __shared__ __align__(16) u16 at[128 * K];

    int tid = threadIdx.x, lane = tid & 63, w = tid >> 6;
    int lr = lane & 15, lg = lane >> 4;
    int m0 = blockIdx.x * 128;
    bool isq = (blockIdx.y == 0);
    const u16* Wt = isq ? Wq : Wk;
    const float* bias = isq ? bq : bk;
    u16* C = isq ? Cq : Ck;

    if (CVTIN) {
        const float* A = (const float*)(isq ? Aq : Ak) + (size_t)m0 * K;
#pragma unroll
        for (int j = 0; j < NCH; j++) {
            int bo = tid * (NCH * 16) + j * 16;       // linear byte offset in bf16 tile
            int row = bo >> 8;                        // K=128: 256 B rows
            int ir = bo & (ROWB - 1);
            const float* src = A + (size_t)row * K + (ir >> 1);
            float4 f0 = *reinterpret_cast<const float4*>(src);
            float4 f1 = *reinterpret_cast<const float4*>(src + 4);
            union { u16 u[8]; uint4 v; } pk;
            {
                __bf16 h;
                h = (__bf16)f0.x; pk.u[0] = *(u16*)&h;
                h = (__bf16)f0.y; pk.u[1] = *(u16*)&h;
                h = (__bf16)f0.z; pk.u[2] = *(u16*)&h;
                h = (__bf16)f0.w; pk.u[3] = *(u16*)&h;
                h = (__bf16)f1.x; pk.u[4] = *(u16*)&h;
                h = (__bf16)f1.y; pk.u[5] = *(u16*)&h;
                h = (__bf16)f1.z; pk.u[6] = *(u16*)&h;
                h = (__bf16)f1.w; pk.u[7] = *(u16*)&h;
            }
            int dst = row * ROWB + (ir ^ ((row & 7) << 4));
            *reinterpret_cast<uint4*>((char*)at + dst) = pk.v;
        }
    } else {
        const char* A = (const char*)((const u16*)(isq ? Aq : Ak) + (size_t)m0 * K);
#pragma unroll
        for (int j = 0; j < NCH; j++) {
            int bo = j * 4096 + tid * 16;             // wave-linear dest
            int row = bo >> 9;                        // K=256: 512 B rows
            int ir = bo & (ROWB - 1);
            int sir = ir ^ ((row & 7) << 4);          // pre-swizzled source
            __builtin_amdgcn_global_load_lds(
                (const __attribute__((address_space(1))) void*)(A + (size_t)row * ROWB + sir),
                (__attribute__((address_space(3))) void*)((char*)at + bo),
                16, 0, 0);
        }
    }
    __syncthreads();

    int n0 = w * 64;
    f32x4 acc[8][4] = {};
#pragma unroll
    for (int ks = 0; ks < K / 32; ks++) {
        bfx8 b[4];
#pragma unroll
        for (int nt = 0; nt < 4; nt++)
            b[nt] = *reinterpret_cast<const bfx8*>(Wt + (size_t)(n0 + nt * 16 + lr) * K + ks * 32 + lg * 8);
#pragma unroll
        for (int mt = 0; mt < 8; mt++) {
            int row = mt * 16 + lr;
            int ir = (ks * 64 + lg * 16) ^ ((lr & 7) << 4);
            bfx8 a = *reinterpret_cast<const bfx8*>((const char*)at + row * ROWB + ir);
#pragma unroll
            for (int nt = 0; nt < 4; nt++)
                acc[mt][nt] = MFMA16(a, b[nt], acc[mt][nt]);
        }
    }

#pragma unroll
    for (int nt = 0; nt < 4; nt++) {
        int col = n0 + nt * 16 + lr;
        float bv = bias[col];
#pragma unroll
        for (int mt = 0; mt < 8; mt++) {
            int rowb = m0 + mt * 16 + lg * 4;
#pragma unroll
            for (int r = 0; r < 4; r++) {
                float v = acc[mt][nt][r] + bv;
                if (RELU) v = fmaxf(v, 0.0f);
                C[(size_t)(rowb + r) * 256 + col] = f2bf(v);
            }
        }
    }
}

// ---------------- pass 1: column stats -> gs[c] = (m_c * log2e, 1/l_c) ----------------
// grid flat 512, XCD-swizzled so each XCD owns 2 batches (L2 locality on q).

__global__ __launch_bounds__(256) void stats_kernel(const u16* __restrict__ q,
                                                    const u16* __restrict__ k,
                                                    float2* __restrict__ gso) {
    int flat = blockIdx.x;
    int sw = (flat & 7) * 64 + (flat >> 3);   // bijective: 512 = 8 * 64
    int b = sw >> 5;
    int c0 = (sw & 31) * 64;
    int tid = threadIdx.x, lane = tid & 63, w = tid >> 6;
    int lr = lane & 15, lg = lane >> 4;
    const u16* qb = q + (size_t)b * NT * DIM;
    const u16* kb = k + (size_t)b * NC * DIM;
    const float scale = 1.0f / 16.0f;

    bfx8 kf[4][8];
#pragma unroll
    for (int j = 0; j < 4; j++)
#pragma unroll
        for (int ks = 0; ks < 8; ks++)
            kf[j][ks] = *reinterpret_cast<const bfx8*>(kb + (size_t)(c0 + j * 16 + lr) * DIM + ks * 32 + lg * 8);

    float m_run[4], l_run[4];
#pragma unroll
    for (int j = 0; j < 4; j++) { m_run[j] = -1e30f; l_run[j] = 0.0f; }

    for (int ts = 0; ts < NT / 64; ts++) {
        int t0 = ts * 64 + w * 16;
        f32x4 acc[4] = {};
#pragma unroll
        for (int ks = 0; ks < 8; ks++) {
            bfx8 a = *reinterpret_cast<const bfx8*>(qb + (size_t)(t0 + lr) * DIM + ks * 32 + lg * 8);
#pragma unroll
            for (int j = 0; j < 4; j++)
                acc[j] = MFMA16(a, kf[j][ks], acc[j]);
        }
#pragma unroll
        for (int j = 0; j < 4; j++) {
            float s0 = acc[j][0] * scale, s1 = acc[j][1] * scale;
            float s2 = acc[j][2] * scale, s3 = acc[j][3] * scale;
            float mx = fmaxf(fmaxf(s0, s1), fmaxf(s2, s3));
            mx = fmaxf(mx, __shfl_xor(mx, 16));
            mx = fmaxf(mx, __shfl_xor(mx, 32));
            float m_new = fmaxf(m_run[j], mx);
            float p = __expf(s0 - m_new) + __expf(s1 - m_new) + __expf(s2 - m_new) + __expf(s3 - m_new);
            p += __shfl_xor(p, 16);
            p += __shfl_xor(p, 32);
            l_run[j] = l_run[j] * __expf(m_run[j] - m_new) + p;
            m_run[j] = m_new;
        }
    }

    __shared__ float sm[4][64], sl[4][64];
    if (lg == 0) {
#pragma unroll
        for (int j = 0; j < 4; j++) {
            sm[w][j * 16 + lr] = m_run[j];
            sl[w][j * 16 + lr] = l_run[j];
        }
    }
    __syncthreads();
    if (tid < 64) {
        float mf = sm[0][tid];
#pragma unroll
        for (int ww = 1; ww < 4; ww++) mf = fmaxf(mf, sm[ww][tid]);
        float lf = 0.0f;
#pragma unroll
        for (int ww = 0; ww < 4; ww++) lf += sl[ww][tid] * __expf(sm[ww][tid] - mf);
        gso[(size_t)b * NC + c0 + tid] = make_float2(mf * 1.44269504f, 1.0f / lf);
    }
}

// ---------------- pass 2: pipelined attention output (T3/T4 + T1 XCD swizzle) ----------

__global__ __launch_bounds__(256, 2) void attn_kernel(const u16* __restrict__ q,
                                                      const u16* __restrict__ k,
                                                      const u16* __restrict__ rt,
                                                      const float2* __restrict__ gsg_,
                                                      float* __restrict__ out) {
    int flat = blockIdx.x;
    int sw = (flat & 7) * 64 + (flat >> 3);   // each XCD -> 2 batches (k+rt fit L2)
    int b = sw >> 5;
    int t0 = (sw & 31) * 64;
    int tid = threadIdx.x, lane = tid & 63, w = tid >> 6;
    int lr = lane & 15, lg = lane >> 4;
    const u16* qb = q + (size_t)b * NT * DIM;
    const u16* kb = k + (size_t)b * NC * DIM;
    const u16* rtb = rt + (size_t)b * DIM * NC;

    __shared__ float2 gs[NC];                       // 16 KB
    __shared__ __align__(16) u16 kt[2][32 * 256];   // 2 x 16 KB, swizzled K tiles
    __shared__ u16 pl[64][36];                      // P tile, 72B rows

    {
        const float2* gsg = gsg_ + (size_t)b * NC;
        for (int i = tid; i < NC; i += 256) gs[i] = gsg[i];
    }
    __syncthreads();

#define STAGE(nb, cc) do {                                                          \
    const u16* ksrc_ = kb + (size_t)(cc) * DIM;                                     \
    _Pragma("unroll")                                                               \
    for (int i_ = 0; i_ < 4; i_++) {                                                \
        int off_ = ((w * 4 + i_) << 10) + (lane << 4);                              \
        int row_ = off_ >> 9;                                                       \
        int ss_  = ((off_ >> 4) & 31) ^ (row_ & 7);                                 \
        const u16* g_ = ksrc_ + row_ * DIM + ss_ * 8;                               \
        __builtin_amdgcn_global_load_lds(                                           \
            (const __attribute__((address_space(1))) void*)g_,                      \
            (__attribute__((address_space(3))) void*)(&kt[nb][(w * 4 + i_) << 9]),  \
            16, 0, 0);                                                              \
    }                                                                               \
} while (0)

    // prologue: stage tile 0, prefetch rb for tile 0, hoist q
    STAGE(0, 0);
    __builtin_amdgcn_sched_barrier(0);
    bfx8 rb_c[4], rb_n[4];
#pragma unroll
    for (int nt = 0; nt < 4; nt++)
        rb_c[nt] = *reinterpret_cast<const bfx8*>(rtb + (size_t)(w * 64 + nt * 16 + lr) * NC + lg * 8);
    bfx8 aq[8];
#pragma unroll
    for (int ks = 0; ks < 8; ks++)
        aq[ks] = *reinterpret_cast<const bfx8*>(qb + (size_t)(t0 + w * 16 + lr) * DIM + ks * 32 + lg * 8);
    __builtin_amdgcn_sched_barrier(0);
    asm volatile("s_waitcnt vmcnt(12)");   // drain 4 stage issues (12 newer: 4 rb + 8 aq)
    __builtin_amdgcn_s_barrier();
    __builtin_amdgcn_sched_barrier(0);

    const float A = 1.44269504f / 16.0f;   // log2e * (1/sqrt(256))
    const int key = lr & 7;
    f32x4 acc[4][4] = {};
    int cur = 0;

    for (int c0 = 0; c0 < NC; c0 += 32) {
        const bool last = (c0 + 32 >= NC);
        if (!last) STAGE(cur ^ 1, c0 + 32);
        __builtin_amdgcn_sched_barrier(0);
        if (!last) {
#pragma unroll
            for (int nt = 0; nt < 4; nt++)
                rb_n[nt] = *reinterpret_cast<const bfx8*>(rtb + (size_t)(w * 64 + nt * 16 + lr) * NC + (c0 + 32) + lg * 8);
        }

        // S phase: read swizzled kt[cur], 16 MFMAs
        f32x4 s[2] = {};
        {
            const char* kc = (const char*)&kt[cur][0];
#pragma unroll
            for (int ks = 0; ks < 8; ks++) {
                int slot = (ks << 2) | lg;
                bfx8 k0 = *reinterpret_cast<const bfx8*>(kc + (lr << 9) + (((slot ^ key)) << 4));
                bfx8 k1 = *reinterpret_cast<const bfx8*>(kc + ((16 + lr) << 9) + (((slot ^ key)) << 4));
                s[0] = MFMA16(aq[ks], k0, s[0]);
                s[1] = MFMA16(aq[ks], k1, s[1]);
            }
        }
        // P = exp2(S*A - m') * invl -> LDS
#pragma unroll
        for (int j = 0; j < 2; j++) {
            float2 g = gs[c0 + j * 16 + lr];
#pragma unroll
            for (int r = 0; r < 4; r++) {
                float p = exp2f(fmaf(s[j][r], A, -g.x)) * g.y;
                __bf16 h = (__bf16)p;
                pl[w * 16 + lg * 4 + r][j * 16 + lr] = *(u16*)&h;
            }
        }
        __builtin_amdgcn_sched_barrier(0);
        asm volatile("s_waitcnt lgkmcnt(0)");
        __builtin_amdgcn_s_barrier();
        __builtin_amdgcn_sched_barrier(0);

        // PV phase
#pragma unroll
        for (int mt = 0; mt < 4; mt++) {
            bfx8a pa = *reinterpret_cast<const bfx8a*>((const char*)pl + (mt * 16 + lr) * 72 + lg * 16);
#pragma unroll
            for (int nt = 0; nt < 4; nt++)
                acc[mt][nt] = MFMA16((bfx8)pa, rb_c[nt], acc[mt][nt]);
        }

        __builtin_amdgcn_sched_barrier(0);
        asm volatile("s_waitcnt vmcnt(4) lgkmcnt(0)");
        __builtin_amdgcn_s_barrier();
        __builtin_amdgcn_sched_barrier(0);

#pragma unroll
        for (int nt = 0; nt < 4; nt++) rb_c[nt] = rb_n[nt];
        cur ^= 1;
    }
#undef STAGE

    float* ob = out + (size_t)b * NT * DIM;
#pragma unroll
    for (int nt = 0; nt < 4; nt++) {
        int col = w * 64 + nt * 16 + lr;
#pragma unroll
        for (int mt = 0; mt < 4; mt++) {
            int rowb = t0 + mt * 16 + lg * 4;
#pragma unroll
            for (int r = 0; r < 4; r++)
                ob[(size_t)(rowb + r) * DIM + col] = acc[mt][nt][r];
        }
    }
}

// ---------------- launch ----------------

extern "C" void kernel_launch(void* const* d_in, const int* in_sizes, int n_in,
                              void* d_out, int out_size, void* d_ws, size_t ws_size,
                              hipStream_t stream) {
    const float* xc  = (const float*)d_in[0];
    const float* xt  = (const float*)d_in[1];
    const float* ri  = (const float*)d_in[2];
    const float* qw1 = (const float*)d_in[3];  const float* qb1 = (const float*)d_in[4];
    const float* qw2 = (const float*)d_in[5];  const float* qb2 = (const float*)d_in[6];
    const float* qw3 = (const float*)d_in[7];  const float* qb3 = (const float*)d_in[8];
    const float* kw1 = (const float*)d_in[9];  const float* kb1 = (const float*)d_in[10];
    const float* kw2 = (const float*)d_in[11]; const float* kb2 = (const float*)d_in[12];
    const float* kw3 = (const float*)d_in[13]; const float* kb3 = (const float*)d_in[14];

    if (ws_size < ((size_t)66 << 20)) return;  // need ~65.2 MB

    char* ws = (char*)d_ws;
    // region A [0,32): h1q/h1k during L1-L2, then q/kk from L3 on
    u16* h1q = (u16*)(ws);
    u16* h1k = (u16*)(ws + ((size_t)16 << 20));
    u16* q   = h1q;
    u16* kk  = h1k;
    // region B [32,64): h2q/h2k during L2-L3, then rt (over h2q) after L3
    u16* h2q = (u16*)(ws + ((size_t)32 << 20));
    u16* h2k = (u16*)(ws + ((size_t)48 << 20));
    u16* rt  = h2q;
    // tail: col stats + weights
    float2* gsb = (float2*)(ws + ((size_t)64 << 20));          // 256 KB
    u16* wbuf = (u16*)(ws + ((size_t)64 << 20) + (512 << 10)); // 640 KB
    u16* qw1t = wbuf;
    u16* qw2t = qw1t + 32768;
    u16* qw3t = qw2t + 65536;
    u16* kw1t = qw3t + 65536;
    u16* kw2t = kw1t + 32768;
    u16* kw3t = kw2t + 65536;

    // weights -> transposed bf16
    cvt_w_kernel<<<dim3(128), 256, 0, stream>>>(qw1, qw1t, 128);
    cvt_w_kernel<<<dim3(256), 256, 0, stream>>>(qw2, qw2t, 256);
    cvt_w_kernel<<<dim3(256), 256, 0, stream>>>(qw3, qw3t, 256);
    cvt_w_kernel<<<dim3(128), 256, 0, stream>>>(kw1, kw1t, 128);
    cvt_w_kernel<<<dim3(256), 256, 0, stream>>>(kw2, kw2t, 256);
    cvt_w_kernel<<<dim3(256), 256, 0, stream>>>(kw3, kw3t, 256);

    // fused MLP (q and k paths in one launch via blockIdx.y)
    mlp_gemm<128, true,  true ><<<dim3(256, 2), 256, 0, stream>>>(xt, xc, qw1t, kw1t, qb1, kb1, h1q, h1k);
    mlp_gemm<256, true,  false><<<dim3(256, 2), 256, 0, stream>>>(h1q, h1k, qw2t, kw2t, qb2, kb2, h2q, h2k);
    mlp_gemm<256, false, false><<<dim3(256, 2), 256, 0, stream>>>(h2q, h2k, qw3t, kw3t, qb3, kb3, q, kk);

    // r_i -> rt (after L3: rt overlays h2q)
    cvt_rt_kernel<<<dim3(64, 8, BB), dim3(32, 8), 0, stream>>>(ri, rt);

    // pass 1: column stats
    stats_kernel<<<dim3(512), 256, 0, stream>>>(q, kk, gsb);

    // pass 2: attention output
    attn_kernel<<<dim3(512), 256, 0, stream>>>(q, kk, rt, gsb, (float*)d_out);
}